// Round 10
// baseline (268.961 us; speedup 1.0000x reference)
//
#include <hip/hip_runtime.h>
#include <hip/hip_bf16.h>

// MultiHeadedSelfAttention: N=2, S=2048, D=1024, H=16, DH=64, fp32 in/out.
// Round 10 (identical to rounds 8/9; both benches were infra failures —
// note round-5/6 infra failures on a source that later PASSED in round 7).
// FULLY FUSED single kernel. Block = 128 q of one (n,h), 4 waves x 32q.
//   - W fragments (Wk as A, Wv as B) loaded global->reg once, persist (L2-hot).
//   - Prologue (barrier-free): per-wave Q projection (A=Wq, B=Xq direct from
//     global), C[e][q] -> pack4 along e -> wave-private Pl -> read back as
//     B-frags qf[q][dh]. Q pre-scaled by log2(e)/8.
//   - Per 64-key tile: X rows direct global->reg; K-proj (A=Wk,B=X) ->
//     Kl[key][dh]; V-proj (A=X,B=Wv) -> Vl[dh][key]; 2 barriers;
//     S^T = K Q^T; per-q-column online softmax (in-reg + 2 shfl, exp2);
//     P via wave-private LDS; O^T = V^T P^T.
//   No intermediate global tensors; d_ws unused.

#define NB 2
#define SS 2048
#define DM 1024
#define NH 16
#define DHd 64

typedef __attribute__((ext_vector_type(8))) short bf16x8;   // 8 bf16 = 4 VGPRs
typedef __attribute__((ext_vector_type(4))) float f32x4;

__device__ __forceinline__ unsigned short f2b(float x) {
    __hip_bfloat16 h = __float2bfloat16(x);
    return *reinterpret_cast<unsigned short*>(&h);
}

__device__ __forceinline__ ushort4 pack4f(float a, float b, float c, float d) {
    ushort4 r; r.x = f2b(a); r.y = f2b(b); r.z = f2b(c); r.w = f2b(d);
    return r;
}

// 8 consecutive fp32 from global -> bf16x8 fragment chunk
__device__ __forceinline__ bf16x8 ld8(const float* p) {
    float4 a = ((const float4*)p)[0];
    float4 b = ((const float4*)p)[1];
    union { bf16x8 v; unsigned short u[8]; } t;
    t.u[0] = f2b(a.x); t.u[1] = f2b(a.y); t.u[2] = f2b(a.z); t.u[3] = f2b(a.w);
    t.u[4] = f2b(b.x); t.u[5] = f2b(b.y); t.u[6] = f2b(b.z); t.u[7] = f2b(b.w);
    return t.v;
}

// [rows][64] bf16 tile, 16B-chunk XOR swizzle (verified conflict-light)
__device__ __forceinline__ int swz(int row, int ch) {
    return row * 64 + ((ch ^ (row & 7)) * 8);
}

#define QSCALE 0.18033688011112042f   // (1/8) * log2(e)

__global__ __launch_bounds__(256) void mhsa(
    const float* __restrict__ seq,
    const float* __restrict__ Wq, const float* __restrict__ bq,
    const float* __restrict__ Wk, const float* __restrict__ bk,
    const float* __restrict__ Wv, const float* __restrict__ bv,
    float* __restrict__ out)
{
    __shared__ unsigned short Kl[64 * 64];      // K-tile [key][dh]   8 KB
    __shared__ unsigned short Vl[64 * 64];      // V-tile [dh][key]   8 KB
    __shared__ unsigned short Pl[4][32 * 64];   // per-wave Q/P [q][key] 16 KB

    const int tid = threadIdx.x;
    const int wv = tid >> 6, L = tid & 63, lo = L & 15, qd = L >> 4;
    const int bi = blockIdx.x;
    const int nh = bi >> 4, qblk = bi & 15;
    const int h = nh & (NH - 1), n = nh >> 4;
    const int q0 = qblk * 128 + wv * 32;        // wave's 32 queries

    const float* Wqh = Wq + h * DHd * DHd;      // [e][d]
    const float* Wkh = Wk + h * DHd * DHd;
    const float* Wvh = Wv + h * DHd * DHd;
    const float* Xn  = seq + (size_t)n * SS * DM + h * DHd;  // + s*DM

    // ---- persistent W fragments (global->reg, L2-hot, 64 VGPRs) ----
    bf16x8 awk[4][2], bwv[4][2];
#pragma unroll
    for (int t = 0; t < 4; ++t)
#pragma unroll
        for (int kt = 0; kt < 2; ++kt) {
            awk[t][kt] = ld8(Wkh + (t * 16 + lo) * DHd + kt * 32 + qd * 8);
            bwv[t][kt] = ld8(Wvh + (t * 16 + lo) * DHd + kt * 32 + qd * 8);
        }
    float4 bkf[4];
    float  bvf[4];
#pragma unroll
    for (int t = 0; t < 4; ++t) {
        bkf[t] = *(const float4*)&bk[h * DHd + t * 16 + qd * 4];
        bvf[t] = bv[h * DHd + t * 16 + lo];
    }

    // ---- prologue: Q projection, wave-private (no barriers) ----
    {
        bf16x8 bxq[2][2];
#pragma unroll
        for (int ct = 0; ct < 2; ++ct)
#pragma unroll
            for (int kt = 0; kt < 2; ++kt)
                bxq[ct][kt] = ld8(Xn + (size_t)(q0 + ct * 16 + lo) * DM
                                  + kt * 32 + qd * 8);
        f32x4 qacc[4][2];
#pragma unroll
        for (int et = 0; et < 4; ++et) {
            float4 bb = *(const float4*)&bq[h * DHd + et * 16 + qd * 4];
#pragma unroll
            for (int ct = 0; ct < 2; ++ct)
                qacc[et][ct] = (f32x4){bb.x, bb.y, bb.z, bb.w};
        }
#pragma unroll
        for (int et = 0; et < 4; ++et)
#pragma unroll
            for (int kt = 0; kt < 2; ++kt) {
                bf16x8 awq = ld8(Wqh + (et * 16 + lo) * DHd + kt * 32 + qd * 8);
#pragma unroll
                for (int ct = 0; ct < 2; ++ct)
                    qacc[et][ct] = __builtin_amdgcn_mfma_f32_16x16x32_bf16(
                        awq, bxq[ct][kt], qacc[et][ct], 0, 0, 0);
            }
        // C[e=et*16+qd*4+reg][q=ct*16+lo] -> Pl[wv] as [q][e], scaled
#pragma unroll
        for (int et = 0; et < 4; ++et)
#pragma unroll
            for (int ct = 0; ct < 2; ++ct)
                *(ushort4*)&Pl[wv][swz(ct * 16 + lo, et * 2 + (qd >> 1))
                                   + (qd & 1) * 4] =
                    pack4f(qacc[et][ct][0] * QSCALE, qacc[et][ct][1] * QSCALE,
                           qacc[et][ct][2] * QSCALE, qacc[et][ct][3] * QSCALE);
    }
    // Q as B-operand: B[n=q=ct*16+lo][k=dh=kt*32+qd*8+j] (wave-private, in-order LDS)
    bf16x8 qf[2][2];
#pragma unroll
    for (int ct = 0; ct < 2; ++ct)
#pragma unroll
        for (int kt = 0; kt < 2; ++kt)
            qf[ct][kt] = *(const bf16x8*)&Pl[wv][swz(ct * 16 + lo, kt * 4 + qd)];

    f32x4 oacc[4][2];          // O^T: [dh-tile][q-tile]
#pragma unroll
    for (int rt = 0; rt < 4; ++rt)
#pragma unroll
        for (int ct = 0; ct < 2; ++ct)
            oacc[rt][ct] = (f32x4){0.f, 0.f, 0.f, 0.f};
    float m[2] = {-1e30f, -1e30f}, l[2] = {0.f, 0.f};

    for (int kv0 = 0; kv0 < SS; kv0 += 64) {
        // X rows for this wave's 16 keys (prefetch before barrier)
        bf16x8 xv[2];
        const float* xrow = Xn + (size_t)(kv0 + wv * 16 + lo) * DM;
#pragma unroll
        for (int kt = 0; kt < 2; ++kt)
            xv[kt] = ld8(xrow + kt * 32 + qd * 8);

        __syncthreads();   // all waves done reading Kl/Vl of previous tile

        // ---- K proj: C[e][key=wv*16+lo] -> Kl[key][dh] (pack4 along e) ----
        f32x4 kacc[4];
#pragma unroll
        for (int et = 0; et < 4; ++et)
            kacc[et] = (f32x4){bkf[et].x, bkf[et].y, bkf[et].z, bkf[et].w};
#pragma unroll
        for (int et = 0; et < 4; ++et)
#pragma unroll
            for (int kt = 0; kt < 2; ++kt)
                kacc[et] = __builtin_amdgcn_mfma_f32_16x16x32_bf16(
                    awk[et][kt], xv[kt], kacc[et], 0, 0, 0);
#pragma unroll
        for (int et = 0; et < 4; ++et)
            *(ushort4*)&Kl[swz(wv * 16 + lo, et * 2 + (qd >> 1)) + (qd & 1) * 4] =
                pack4f(kacc[et][0], kacc[et][1], kacc[et][2], kacc[et][3]);

        // ---- V proj: C[key=wv*16+qd*4+reg][dh] -> Vl[dh][key] (pack4 along key) ----
        f32x4 vacc[4];
#pragma unroll
        for (int dt = 0; dt < 4; ++dt)
            vacc[dt] = (f32x4){bvf[dt], bvf[dt], bvf[dt], bvf[dt]};
#pragma unroll
        for (int dt = 0; dt < 4; ++dt)
#pragma unroll
            for (int kt = 0; kt < 2; ++kt)
                vacc[dt] = __builtin_amdgcn_mfma_f32_16x16x32_bf16(
                    xv[kt], bwv[dt][kt], vacc[dt], 0, 0, 0);
#pragma unroll
        for (int dt = 0; dt < 4; ++dt)
            *(ushort4*)&Vl[swz(dt * 16 + lo, wv * 2 + (qd >> 1)) + (qd & 1) * 4] =
                pack4f(vacc[dt][0], vacc[dt][1], vacc[dt][2], vacc[dt][3]);

        __syncthreads();   // Kl/Vl tile ready

        // ---- S^T = K Q^T : C[key=rt*16+qd*4+reg][q=ct*16+lo] ----
        f32x4 sacc[4][2];
#pragma unroll
        for (int rt = 0; rt < 4; ++rt)
#pragma unroll
            for (int ct = 0; ct < 2; ++ct)
                sacc[rt][ct] = (f32x4){0.f, 0.f, 0.f, 0.f};
#pragma unroll
        for (int rt = 0; rt < 4; ++rt)
#pragma unroll
            for (int kt = 0; kt < 2; ++kt) {
                bf16x8 kf = *(const bf16x8*)&Kl[swz(rt * 16 + lo, kt * 4 + qd)];
#pragma unroll
                for (int ct = 0; ct < 2; ++ct)
                    sacc[rt][ct] = __builtin_amdgcn_mfma_f32_16x16x32_bf16(
                        kf, qf[ct][kt], sacc[rt][ct], 0, 0, 0);
            }

        // ---- online softmax per q column (log2 domain) ----
#pragma unroll
        for (int ct = 0; ct < 2; ++ct) {
            float mx = sacc[0][ct][0];
#pragma unroll
            for (int rt = 0; rt < 4; ++rt)
#pragma unroll
                for (int r = 0; r < 4; ++r) mx = fmaxf(mx, sacc[rt][ct][r]);
            mx = fmaxf(mx, __shfl_xor(mx, 16, 64));
            mx = fmaxf(mx, __shfl_xor(mx, 32, 64));
            const float mn = fmaxf(m[ct], mx);
            const bool up = __any(mn > m[ct]);
            float rs = 0.f;
#pragma unroll
            for (int rt = 0; rt < 4; ++rt) {
                float p0 = exp2f(sacc[rt][ct][0] - mn);
                float p1 = exp2f(sacc[rt][ct][1] - mn);
                float p2 = exp2f(sacc[rt][ct][2] - mn);
                float p3 = exp2f(sacc[rt][ct][3] - mn);
                rs += (p0 + p1) + (p2 + p3);
                *(ushort4*)&Pl[wv][swz(ct * 16 + lo, rt * 2 + (qd >> 1))
                                   + (qd & 1) * 4] = pack4f(p0, p1, p2, p3);
            }
            rs += __shfl_xor(rs, 16, 64);
            rs += __shfl_xor(rs, 32, 64);
            if (up) {
                const float corr = exp2f(m[ct] - mn);
                l[ct] *= corr;
#pragma unroll
                for (int rt = 0; rt < 4; ++rt)
#pragma unroll
                    for (int r = 0; r < 4; ++r) oacc[rt][ct][r] *= corr;
                m[ct] = mn;
            }
            l[ct] += rs;
        }

        // ---- O^T += V^T P^T : A=Vl[dh][key], B=Pl[q][key] ----
#pragma unroll
        for (int kt = 0; kt < 2; ++kt) {
            bf16x8 pf[2];
#pragma unroll
            for (int ct = 0; ct < 2; ++ct)
                pf[ct] = *(const bf16x8*)&Pl[wv][swz(ct * 16 + lo, kt * 4 + qd)];
#pragma unroll
            for (int rt = 0; rt < 4; ++rt) {
                bf16x8 vf = *(const bf16x8*)&Vl[swz(rt * 16 + lo, kt * 4 + qd)];
#pragma unroll
                for (int ct = 0; ct < 2; ++ct)
                    oacc[rt][ct] = __builtin_amdgcn_mfma_f32_16x16x32_bf16(
                        vf, pf[ct], oacc[rt][ct], 0, 0, 0);
            }
        }
    }

    // ---- epilogue: lane holds O^T[dh=rt*16+qd*4+reg][q=ct*16+lo] ----
#pragma unroll
    for (int ct = 0; ct < 2; ++ct) {
        const float inv = 1.0f / l[ct];
        const int s = q0 + ct * 16 + lo;
#pragma unroll
        for (int rt = 0; rt < 4; ++rt) {
            float4 o;
            o.x = oacc[rt][ct][0] * inv; o.y = oacc[rt][ct][1] * inv;
            o.z = oacc[rt][ct][2] * inv; o.w = oacc[rt][ct][3] * inv;
            *(float4*)&out[((size_t)n * SS + s) * DM + h * DHd
                           + rt * 16 + qd * 4] = o;
        }
    }
}

extern "C" void kernel_launch(void* const* d_in, const int* in_sizes, int n_in,
                              void* d_out, int out_size, void* d_ws, size_t ws_size,
                              hipStream_t stream) {
    const float* seq = (const float*)d_in[0];
    const float* Wq  = (const float*)d_in[1];
    const float* bq  = (const float*)d_in[2];
    const float* Wk  = (const float*)d_in[3];
    const float* bk  = (const float*)d_in[4];
    const float* Wv  = (const float*)d_in[5];
    const float* bv  = (const float*)d_in[6];
    float* out = (float*)d_out;

    mhsa<<<512, 256, 0, stream>>>(seq, Wq, bq, Wk, bk, Wv, bv, out);
}

// Round 12
// 165.238 us; speedup vs baseline: 1.6277x; 1.6277x over previous
//
#include <hip/hip_runtime.h>
#include <hip/hip_bf16.h>

// MultiHeadedSelfAttention: N=2, S=2048, D=1024, H=16, DH=64, fp32 in/out.
// Round 12 (identical to round 11; bench was an infra failure).
// attn = round-3 kernel VERBATIM (measured 81us). Experiment is qkv_proj:
// round-3 MFMA structure, but C-fragment stores bounce through LDS (reusing
// dead Xl) so global stores are fully coalesced (r3-r7 qkv was ~75us,
// theory: 8B-scattered stores w/ ~8x write amplification).

#define NB 2
#define SS 2048
#define DM 1024
#define NH 16
#define DHd 64

typedef __attribute__((ext_vector_type(8))) short bf16x8;   // 8 bf16 = 4 VGPRs
typedef __attribute__((ext_vector_type(4))) float f32x4;

__device__ __forceinline__ unsigned short f2b(float x) {
    __hip_bfloat16 h = __float2bfloat16(x);
    return *reinterpret_cast<unsigned short*>(&h);
}

__device__ __forceinline__ ushort4 pack4f(float a, float b, float c, float d) {
    ushort4 r; r.x = f2b(a); r.y = f2b(b); r.z = f2b(c); r.w = f2b(d);
    return r;
}

__device__ __forceinline__ bf16x8 pack8(float4 a, float4 b) {
    union { bf16x8 v; unsigned short u[8]; } t;
    t.u[0] = f2b(a.x); t.u[1] = f2b(a.y); t.u[2] = f2b(a.z); t.u[3] = f2b(a.w);
    t.u[4] = f2b(b.x); t.u[5] = f2b(b.y); t.u[6] = f2b(b.z); t.u[7] = f2b(b.w);
    return t.v;
}

// [rows][64] bf16 tile, 16B-chunk XOR swizzle (0 conflicts measured, round 2)
__device__ __forceinline__ int swz(int row, int ch) {
    return row * 64 + ((ch ^ (row & 7)) * 8);
}

__global__ __launch_bounds__(256) void qkv_proj(
    const float* __restrict__ seq,
    const float* __restrict__ Wq, const float* __restrict__ bq,
    const float* __restrict__ Wk, const float* __restrict__ bk,
    const float* __restrict__ Wv, const float* __restrict__ bv,
    unsigned short* __restrict__ Q, unsigned short* __restrict__ K,
    unsigned short* __restrict__ Vt)
{
    __shared__ unsigned short Xl[128 * 64];      // staging 16 KB, then bounce
    __shared__ unsigned short Wl[3 * 64 * 64];   // 24 KB

    const int tid = threadIdx.x;
    const int wv = tid >> 6, L = tid & 63, lo = L & 15, qd = L >> 4;
    const int bi = blockIdx.x;
    const int nh = bi >> 4, sb = bi & 15;
    const int h = nh & (NH - 1), n = nh >> 4;
    const int s0 = sb * 128;

    // ---- stage X tile (fp32 -> bf16, swizzled; coalesced 2KB/instr) ----
#pragma unroll
    for (int i = 0; i < 4; ++i) {
        int idx = tid + i * 256;
        int r = idx >> 3, ch = idx & 7;
        const float* src = seq + ((size_t)(n * SS + s0 + r)) * DM + h * DHd + ch * 8;
        float4 a = ((const float4*)src)[0];
        float4 b = ((const float4*)src)[1];
        *(bf16x8*)&Xl[swz(r, ch)] = pack8(a, b);
    }
    // ---- stage Wq, Wk, Wv ----
#pragma unroll
    for (int i = 0; i < 6; ++i) {
        int idx = tid + i * 256;
        int mat = idx >> 9;                    // uniform per i
        int rem = idx & 511;
        int e = rem >> 3, ch = rem & 7;
        const float* Wm = (mat == 0) ? Wq : (mat == 1) ? Wk : Wv;
        const float* src = Wm + (size_t)(h * DHd + e) * DHd + ch * 8;
        float4 a = ((const float4*)src)[0];
        float4 b = ((const float4*)src)[1];
        *(bf16x8*)&Wl[mat * 4096 + swz(e, ch)] = pack8(a, b);
    }
    __syncthreads();

    // X fragments (B-operand for Q/K, A-operand for V): rows wv*32+st*16+lo
    bf16x8 xf[2][2];
#pragma unroll
    for (int st = 0; st < 2; ++st)
#pragma unroll
        for (int kt = 0; kt < 2; ++kt)
            xf[st][kt] = *(const bf16x8*)&Xl[swz(wv * 32 + st * 16 + lo, kt * 4 + qd)];
    __syncthreads();   // Xl dead -> becomes the store-bounce buffer

    // ---- Q and K: transposed form. C row = e = et*16+qd*4+reg, col = s ----
#pragma unroll
    for (int m2 = 0; m2 < 2; ++m2) {
        const unsigned short* Wb = &Wl[m2 * 4096];
        const float* bias = m2 ? bk : bq;
        unsigned short* O = m2 ? K : Q;
        const float sc = m2 ? 1.0f : 0.125f;   // Q pre-scaled by 1/sqrt(64)

        f32x4 acc[4][2];
#pragma unroll
        for (int et = 0; et < 4; ++et) {
            float4 bb = *(const float4*)&bias[h * DHd + et * 16 + qd * 4];
#pragma unroll
            for (int st = 0; st < 2; ++st)
                acc[et][st] = (f32x4){bb.x, bb.y, bb.z, bb.w};
        }
#pragma unroll
        for (int et = 0; et < 4; ++et) {
            bf16x8 wf0 = *(const bf16x8*)&Wb[swz(et * 16 + lo, qd)];
            bf16x8 wf1 = *(const bf16x8*)&Wb[swz(et * 16 + lo, 4 + qd)];
#pragma unroll
            for (int st = 0; st < 2; ++st) {
                acc[et][st] = __builtin_amdgcn_mfma_f32_16x16x32_bf16(
                    wf0, xf[st][0], acc[et][st], 0, 0, 0);
                acc[et][st] = __builtin_amdgcn_mfma_f32_16x16x32_bf16(
                    wf1, xf[st][1], acc[et][st], 0, 0, 0);
            }
        }
        // bounce: wave-private [s][e] slice of Xl (rows wv*32..wv*32+31)
#pragma unroll
        for (int et = 0; et < 4; ++et)
#pragma unroll
            for (int st = 0; st < 2; ++st) {
                int row = wv * 32 + st * 16 + lo;
                *(ushort4*)&Xl[swz(row, et * 2 + (qd >> 1)) + (qd & 1) * 4] =
                    pack4f(acc[et][st][0] * sc, acc[et][st][1] * sc,
                           acc[et][st][2] * sc, acc[et][st][3] * sc);
            }
        // wave-private readout -> coalesced 1KB-per-instr global stores
#pragma unroll
        for (int i = 0; i < 4; ++i) {
            int r = wv * 32 + i * 8 + (L >> 3);
            int ch = L & 7;
            uint4 v = *(const uint4*)&Xl[swz(r, ch)];
            *(uint4*)&O[((size_t)nh * SS + s0 + r) * DHd + ch * 8] = v;
        }
    }

    // ---- V: direct form. C row = s = st*16+qd*4+reg, col = e = et*16+lo ----
    __syncthreads();   // all Q/K readouts done before V re-layout of Xl
    {
        const unsigned short* Wb = &Wl[2 * 4096];
        float bvv[4];
#pragma unroll
        for (int et = 0; et < 4; ++et) bvv[et] = bv[h * DHd + et * 16 + lo];

        f32x4 acc[2][4];
#pragma unroll
        for (int st = 0; st < 2; ++st)
#pragma unroll
            for (int et = 0; et < 4; ++et)
                acc[st][et] = (f32x4){bvv[et], bvv[et], bvv[et], bvv[et]};
#pragma unroll
        for (int et = 0; et < 4; ++et) {
            bf16x8 wf0 = *(const bf16x8*)&Wb[swz(et * 16 + lo, qd)];
            bf16x8 wf1 = *(const bf16x8*)&Wb[swz(et * 16 + lo, 4 + qd)];
#pragma unroll
            for (int st = 0; st < 2; ++st) {
                acc[st][et] = __builtin_amdgcn_mfma_f32_16x16x32_bf16(
                    xf[st][0], wf0, acc[st][et], 0, 0, 0);
                acc[st][et] = __builtin_amdgcn_mfma_f32_16x16x32_bf16(
                    xf[st][1], wf1, acc[st][et], 0, 0, 0);
            }
        }
        // bounce: block-wide Xl viewed as [64 e][128 s], 16-chunk XOR swizzle
#pragma unroll
        for (int st = 0; st < 2; ++st)
#pragma unroll
            for (int et = 0; et < 4; ++et) {
                int e = et * 16 + lo;
                int ch = wv * 4 + st * 2 + (qd >> 1);   // logical s-chunk 0..15
                *(ushort4*)&Xl[e * 128 + ((ch ^ (e & 15)) * 8) + (qd & 1) * 4] =
                    pack4f(acc[st][et][0], acc[st][et][1],
                           acc[st][et][2], acc[st][et][3]);
            }
        __syncthreads();
        // block-wide readout -> 256B-contiguous global stores
#pragma unroll
        for (int i = 0; i < 4; ++i) {
            int e = i * 16 + (tid >> 4);
            int ch = tid & 15;
            uint4 v = *(const uint4*)&Xl[e * 128 + ((ch ^ (e & 15)) * 8)];
            *(uint4*)&Vt[((size_t)nh * DHd + e) * SS + s0 + ch * 8] = v;
        }
    }
}

#define PSTR 72   // round-3 P row stride (bf16)

__global__ __launch_bounds__(256) void attn(
    const unsigned short* __restrict__ Qg, const unsigned short* __restrict__ Kg,
    const unsigned short* __restrict__ Vg, float* __restrict__ out)
{
    __shared__ unsigned short Kl[64 * 64];          // [key][dh]  8 KB
    __shared__ unsigned short Vl[64 * 64];          // [dh][key]  8 KB
    __shared__ unsigned short Pl[4][32 * PSTR];     // per-wave [q][key] 18 KB

    const int tid = threadIdx.x;
    const int wv = tid >> 6, L = tid & 63, lo = L & 15, qd = L >> 4;
    const int bi = blockIdx.x;
    const int nh = bi >> 4, qblk = bi & 15;
    const int h = nh & (NH - 1), n = nh >> 4;
    const int q0 = qblk * 128 + wv * 32;

    const unsigned short* Qnh = Qg + (size_t)nh * SS * DHd;
    const unsigned short* Knh = Kg + (size_t)nh * SS * DHd;
    const unsigned short* Vnh = Vg + (size_t)nh * DHd * SS;   // [dh][s]

    // Q as B-operand: B[n=q=ct*16+lo][k=dh=kt*32+qd*8+j]
    bf16x8 qf[2][2];
#pragma unroll
    for (int ct = 0; ct < 2; ++ct)
#pragma unroll
        for (int kt = 0; kt < 2; ++kt)
            qf[ct][kt] = *(const bf16x8*)(Qnh + (size_t)(q0 + ct * 16 + lo) * DHd
                                          + kt * 32 + qd * 8);

    f32x4 oacc[4][2];          // O^T: [dh-tile][q-tile], row=dh, col=q
#pragma unroll
    for (int rt = 0; rt < 4; ++rt)
#pragma unroll
        for (int ct = 0; ct < 2; ++ct)
            oacc[rt][ct] = (f32x4){0.f, 0.f, 0.f, 0.f};

    float m[2] = {-1e30f, -1e30f}, l[2] = {0.f, 0.f};

    for (int kv0 = 0; kv0 < SS; kv0 += 64) {
        __syncthreads();
#pragma unroll
        for (int i = 0; i < 2; ++i) {
            int idx = tid + i * 256;
            int r = idx >> 3, ch = idx & 7;
            *(uint4*)&Kl[swz(r, ch)] =
                *(const uint4*)(Knh + (size_t)(kv0 + r) * DHd + ch * 8);
            *(uint4*)&Vl[swz(r, ch)] =
                *(const uint4*)(Vnh + (size_t)r * SS + kv0 + ch * 8);
        }
        __syncthreads();

        // ---- S^T = K Q^T : C[row=key=rt*16+qd*4+reg][col=q=ct*16+lo] ----
        f32x4 sacc[4][2];
#pragma unroll
        for (int rt = 0; rt < 4; ++rt)
#pragma unroll
            for (int ct = 0; ct < 2; ++ct)
                sacc[rt][ct] = (f32x4){0.f, 0.f, 0.f, 0.f};
#pragma unroll
        for (int rt = 0; rt < 4; ++rt)
#pragma unroll
            for (int kt = 0; kt < 2; ++kt) {
                bf16x8 kf = *(const bf16x8*)&Kl[swz(rt * 16 + lo, kt * 4 + qd)];
#pragma unroll
                for (int ct = 0; ct < 2; ++ct)
                    sacc[rt][ct] = __builtin_amdgcn_mfma_f32_16x16x32_bf16(
                        kf, qf[ct][kt], sacc[rt][ct], 0, 0, 0);
            }

        // ---- online softmax per q-column (in-register + 2 shfl) ----
#pragma unroll
        for (int ct = 0; ct < 2; ++ct) {
            float mx = sacc[0][ct][0];
#pragma unroll
            for (int rt = 0; rt < 4; ++rt)
#pragma unroll
                for (int r = 0; r < 4; ++r)
                    mx = fmaxf(mx, sacc[rt][ct][r]);
            mx = fmaxf(mx, __shfl_xor(mx, 16, 64));
            mx = fmaxf(mx, __shfl_xor(mx, 32, 64));
            const float mo = m[ct];
            const float mn = fmaxf(mo, mx);
            const float corr = __expf(mo - mn);
            float rs = 0.f;
#pragma unroll
            for (int rt = 0; rt < 4; ++rt) {
                float p0 = __expf(sacc[rt][ct][0] - mn);
                float p1 = __expf(sacc[rt][ct][1] - mn);
                float p2 = __expf(sacc[rt][ct][2] - mn);
                float p3 = __expf(sacc[rt][ct][3] - mn);
                rs += (p0 + p1) + (p2 + p3);
                ushort4 w;
                w.x = f2b(p0); w.y = f2b(p1); w.z = f2b(p2); w.w = f2b(p3);
                *(ushort4*)&Pl[wv][(ct * 16 + lo) * PSTR + rt * 16 + qd * 4] = w;
            }
            rs += __shfl_xor(rs, 16, 64);
            rs += __shfl_xor(rs, 32, 64);
            l[ct] = l[ct] * corr + rs;
            m[ct] = mn;
#pragma unroll
            for (int rt = 0; rt < 4; ++rt)
#pragma unroll
                for (int r = 0; r < 4; ++r)
                    oacc[rt][ct][r] *= corr;
        }

        // ---- O^T += V^T P^T : A=V^T[dh][key], B=P[q][key] ----
#pragma unroll
        for (int kt = 0; kt < 2; ++kt) {
            bf16x8 pf[2];
#pragma unroll
            for (int ct = 0; ct < 2; ++ct)
                pf[ct] = *(const bf16x8*)&Pl[wv][(ct * 16 + lo) * PSTR
                                                 + kt * 32 + qd * 8];
#pragma unroll
            for (int rt = 0; rt < 4; ++rt) {
                bf16x8 vf = *(const bf16x8*)&Vl[swz(rt * 16 + lo, kt * 4 + qd)];
#pragma unroll
                for (int ct = 0; ct < 2; ++ct)
                    oacc[rt][ct] = __builtin_amdgcn_mfma_f32_16x16x32_bf16(
                        vf, pf[ct], oacc[rt][ct], 0, 0, 0);
            }
        }
    }

    // ---- epilogue: lane holds O^T[dh=rt*16+qd*4+reg][q=ct*16+lo] ----
#pragma unroll
    for (int ct = 0; ct < 2; ++ct) {
        const float inv = 1.0f / l[ct];
        const int s = q0 + ct * 16 + lo;
#pragma unroll
        for (int rt = 0; rt < 4; ++rt) {
            float4 o;
            o.x = oacc[rt][ct][0] * inv; o.y = oacc[rt][ct][1] * inv;
            o.z = oacc[rt][ct][2] * inv; o.w = oacc[rt][ct][3] * inv;
            *(float4*)&out[((size_t)n * SS + s) * DM + h * DHd
                           + rt * 16 + qd * 4] = o;
        }
    }
}

extern "C" void kernel_launch(void* const* d_in, const int* in_sizes, int n_in,
                              void* d_out, int out_size, void* d_ws, size_t ws_size,
                              hipStream_t stream) {
    const float* seq = (const float*)d_in[0];
    const float* Wq  = (const float*)d_in[1];
    const float* bq  = (const float*)d_in[2];
    const float* Wk  = (const float*)d_in[3];
    const float* bk  = (const float*)d_in[4];
    const float* Wv  = (const float*)d_in[5];
    const float* bv  = (const float*)d_in[6];
    float* out = (float*)d_out;

    const size_t per = (size_t)NB * NH * SS * DHd;  // 4.19M bf16 = 8.4 MB each
    unsigned short* Q  = (unsigned short*)d_ws;
    unsigned short* K  = Q + per;
    unsigned short* Vt = K + per;

    qkv_proj<<<512, 256, 0, stream>>>(seq, Wq, bq, Wk, bk, Wv, bv, Q, K, Vt);
    attn<<<512, 256, 0, stream>>>(Q, K, Vt, out);
}

// Round 13
// 161.751 us; speedup vs baseline: 1.6628x; 1.0216x over previous
//
#include <hip/hip_runtime.h>
#include <hip/hip_bf16.h>

// MultiHeadedSelfAttention: N=2, S=2048, D=1024, H=16, DH=64, fp32 in/out.
// Round 13. Ledger insight (r10/r12): dur_us carries ~62us fixed harness
// overhead; qkv is only ~14us. All effort on attn (82us):
//   attn: 128-key tiles (half the barriers), exp2-domain softmax with
//         wave-uniform rescale-skip, XCD swizzle bi=qblk*32+nh so same-nh
//         blocks share an XCD L2 (K+V 2MB fits 4MB).
//   qkv: round-3 version verbatim (fastest measured), QSCALE=log2(e)/8.

#define NB 2
#define SS 2048
#define DM 1024
#define NH 16
#define DHd 64

typedef __attribute__((ext_vector_type(8))) short bf16x8;   // 8 bf16 = 4 VGPRs
typedef __attribute__((ext_vector_type(4))) float f32x4;

__device__ __forceinline__ unsigned short f2b(float x) {
    __hip_bfloat16 h = __float2bfloat16(x);
    return *reinterpret_cast<unsigned short*>(&h);
}

__device__ __forceinline__ ushort4 pack4f(float a, float b, float c, float d) {
    ushort4 r; r.x = f2b(a); r.y = f2b(b); r.z = f2b(c); r.w = f2b(d);
    return r;
}

__device__ __forceinline__ bf16x8 pack8(float4 a, float4 b) {
    union { bf16x8 v; unsigned short u[8]; } t;
    t.u[0] = f2b(a.x); t.u[1] = f2b(a.y); t.u[2] = f2b(a.z); t.u[3] = f2b(a.w);
    t.u[4] = f2b(b.x); t.u[5] = f2b(b.y); t.u[6] = f2b(b.z); t.u[7] = f2b(b.w);
    return t.v;
}

// [rows][64] bf16 tile, 8x16B-chunk XOR swizzle (0 conflicts measured, r2)
__device__ __forceinline__ int swz(int row, int ch) {
    return row * 64 + ((ch ^ (row & 7)) * 8);
}
// [rows][128] bf16 tile, 16x16B-chunk XOR swizzle
__device__ __forceinline__ int swzV(int row, int ch) {
    return row * 128 + ((ch ^ (row & 15)) * 8);
}

#define QSCALE 0.18033688011112042f   // (1/8) * log2(e)

__global__ __launch_bounds__(256) void qkv_proj(
    const float* __restrict__ seq,
    const float* __restrict__ Wq, const float* __restrict__ bq,
    const float* __restrict__ Wk, const float* __restrict__ bk,
    const float* __restrict__ Wv, const float* __restrict__ bv,
    unsigned short* __restrict__ Q, unsigned short* __restrict__ K,
    unsigned short* __restrict__ Vt)
{
    __shared__ unsigned short Xl[128 * 64];      // 16 KB
    __shared__ unsigned short Wl[3 * 64 * 64];   // 24 KB

    const int tid = threadIdx.x;
    const int wv = tid >> 6, L = tid & 63, lo = L & 15, qd = L >> 4;
    const int bi = blockIdx.x;
    const int nh = bi >> 4, sb = bi & 15;
    const int h = nh & (NH - 1), n = nh >> 4;
    const int s0 = sb * 128;

#pragma unroll
    for (int i = 0; i < 4; ++i) {
        int idx = tid + i * 256;
        int r = idx >> 3, ch = idx & 7;
        const float* src = seq + ((size_t)(n * SS + s0 + r)) * DM + h * DHd + ch * 8;
        float4 a = ((const float4*)src)[0];
        float4 b = ((const float4*)src)[1];
        *(bf16x8*)&Xl[swz(r, ch)] = pack8(a, b);
    }
#pragma unroll
    for (int i = 0; i < 6; ++i) {
        int idx = tid + i * 256;
        int mat = idx >> 9;
        int rem = idx & 511;
        int e = rem >> 3, ch = rem & 7;
        const float* Wm = (mat == 0) ? Wq : (mat == 1) ? Wk : Wv;
        const float* src = Wm + (size_t)(h * DHd + e) * DHd + ch * 8;
        float4 a = ((const float4*)src)[0];
        float4 b = ((const float4*)src)[1];
        *(bf16x8*)&Wl[mat * 4096 + swz(e, ch)] = pack8(a, b);
    }
    __syncthreads();

    bf16x8 xf[2][2];
#pragma unroll
    for (int st = 0; st < 2; ++st)
#pragma unroll
        for (int kt = 0; kt < 2; ++kt)
            xf[st][kt] = *(const bf16x8*)&Xl[swz(wv * 32 + st * 16 + lo, kt * 4 + qd)];

    // ---- Q/K transposed form: C row = e = et*16+qd*4+reg, col = s ----
#pragma unroll
    for (int m2 = 0; m2 < 2; ++m2) {
        const unsigned short* Wb = &Wl[m2 * 4096];
        const float* bias = m2 ? bk : bq;
        unsigned short* O = m2 ? K : Q;
        const float sc = m2 ? 1.0f : QSCALE;

        f32x4 acc[4][2];
#pragma unroll
        for (int et = 0; et < 4; ++et) {
            float4 bb = *(const float4*)&bias[h * DHd + et * 16 + qd * 4];
#pragma unroll
            for (int st = 0; st < 2; ++st)
                acc[et][st] = (f32x4){bb.x, bb.y, bb.z, bb.w};
        }
#pragma unroll
        for (int et = 0; et < 4; ++et) {
            bf16x8 wf0 = *(const bf16x8*)&Wb[swz(et * 16 + lo, qd)];
            bf16x8 wf1 = *(const bf16x8*)&Wb[swz(et * 16 + lo, 4 + qd)];
#pragma unroll
            for (int st = 0; st < 2; ++st) {
                acc[et][st] = __builtin_amdgcn_mfma_f32_16x16x32_bf16(
                    wf0, xf[st][0], acc[et][st], 0, 0, 0);
                acc[et][st] = __builtin_amdgcn_mfma_f32_16x16x32_bf16(
                    wf1, xf[st][1], acc[et][st], 0, 0, 0);
            }
        }
#pragma unroll
        for (int et = 0; et < 4; ++et)
#pragma unroll
            for (int st = 0; st < 2; ++st) {
                int s = s0 + wv * 32 + st * 16 + lo;
                ushort4 w = pack4f(acc[et][st][0] * sc, acc[et][st][1] * sc,
                                   acc[et][st][2] * sc, acc[et][st][3] * sc);
                *(ushort4*)&O[((size_t)nh * SS + s) * DHd + et * 16 + qd * 4] = w;
            }
    }

    // ---- V direct form: C row = s, col = e ----
    {
        const unsigned short* Wb = &Wl[2 * 4096];
        float bvv[4];
#pragma unroll
        for (int et = 0; et < 4; ++et) bvv[et] = bv[h * DHd + et * 16 + lo];

        f32x4 acc[2][4];
#pragma unroll
        for (int st = 0; st < 2; ++st)
#pragma unroll
            for (int et = 0; et < 4; ++et)
                acc[st][et] = (f32x4){bvv[et], bvv[et], bvv[et], bvv[et]};
#pragma unroll
        for (int et = 0; et < 4; ++et) {
            bf16x8 wf0 = *(const bf16x8*)&Wb[swz(et * 16 + lo, qd)];
            bf16x8 wf1 = *(const bf16x8*)&Wb[swz(et * 16 + lo, 4 + qd)];
#pragma unroll
            for (int st = 0; st < 2; ++st) {
                acc[st][et] = __builtin_amdgcn_mfma_f32_16x16x32_bf16(
                    xf[st][0], wf0, acc[st][et], 0, 0, 0);
                acc[st][et] = __builtin_amdgcn_mfma_f32_16x16x32_bf16(
                    xf[st][1], wf1, acc[st][et], 0, 0, 0);
            }
        }
#pragma unroll
        for (int st = 0; st < 2; ++st)
#pragma unroll
            for (int et = 0; et < 4; ++et) {
                int e = et * 16 + lo;
                int s = s0 + wv * 32 + st * 16 + qd * 4;
                ushort4 w = pack4f(acc[st][et][0], acc[st][et][1],
                                   acc[st][et][2], acc[st][et][3]);
                *(ushort4*)&Vt[((size_t)nh * DHd + e) * SS + s] = w;
            }
    }
}

#define PSTR 136   // P row stride (bf16) for 128-key tile: stride 68 dw, %32=4

__global__ __launch_bounds__(256) void attn(
    const unsigned short* __restrict__ Qg, const unsigned short* __restrict__ Kg,
    const unsigned short* __restrict__ Vg, float* __restrict__ out)
{
    __shared__ unsigned short Kl[128 * 64];         // [key][dh]   16 KB
    __shared__ unsigned short Vl[64 * 128];         // [dh][key]   16 KB
    __shared__ unsigned short Pl[4][32 * PSTR];     // [q][key]    34 KB

    const int tid = threadIdx.x;
    const int wv = tid >> 6, L = tid & 63, lo = L & 15, qd = L >> 4;
    const int bi = blockIdx.x;
    const int nh = bi & 31, qblk = bi >> 5;     // bi%8 = nh%8 -> XCD grouping
    const int h = nh & (NH - 1), n = nh >> 4;
    const int q0 = qblk * 128 + wv * 32;

    const unsigned short* Qnh = Qg + (size_t)nh * SS * DHd;
    const unsigned short* Knh = Kg + (size_t)nh * SS * DHd;
    const unsigned short* Vnh = Vg + (size_t)nh * DHd * SS;   // [dh][s]

    // Q as B-operand: B[n=q=ct*16+lo][k=dh=kt*32+qd*8+j] (log2-domain scaled)
    bf16x8 qf[2][2];
#pragma unroll
    for (int ct = 0; ct < 2; ++ct)
#pragma unroll
        for (int kt = 0; kt < 2; ++kt)
            qf[ct][kt] = *(const bf16x8*)(Qnh + (size_t)(q0 + ct * 16 + lo) * DHd
                                          + kt * 32 + qd * 8);

    f32x4 oacc[4][2];          // O^T: [dh-tile][q-tile]
#pragma unroll
    for (int rt = 0; rt < 4; ++rt)
#pragma unroll
        for (int ct = 0; ct < 2; ++ct)
            oacc[rt][ct] = (f32x4){0.f, 0.f, 0.f, 0.f};

    float m[2] = {-1e30f, -1e30f}, l[2] = {0.f, 0.f};

    for (int kv0 = 0; kv0 < SS; kv0 += 128) {
        __syncthreads();
        // ---- stage 128-key K tile and V^T tile ----
#pragma unroll
        for (int i = 0; i < 4; ++i) {
            int idx = tid + i * 256;            // 0..1023
            int rk = idx >> 3, chk = idx & 7;   // K: key 0..127
            *(uint4*)&Kl[swz(rk, chk)] =
                *(const uint4*)(Knh + (size_t)(kv0 + rk) * DHd + chk * 8);
            int rv = idx >> 4, chv = idx & 15;  // V: dh 0..63
            *(uint4*)&Vl[swzV(rv, chv)] =
                *(const uint4*)(Vnh + (size_t)rv * SS + kv0 + chv * 8);
        }
        __syncthreads();

        // ---- S^T = K Q^T : C[key=rt*16+qd*4+reg][q=ct*16+lo], rt 0..7 ----
        f32x4 sacc[8][2];
#pragma unroll
        for (int rt = 0; rt < 8; ++rt)
#pragma unroll
            for (int ct = 0; ct < 2; ++ct)
                sacc[rt][ct] = (f32x4){0.f, 0.f, 0.f, 0.f};
#pragma unroll
        for (int rt = 0; rt < 8; ++rt)
#pragma unroll
            for (int kt = 0; kt < 2; ++kt) {
                bf16x8 kf = *(const bf16x8*)&Kl[swz(rt * 16 + lo, kt * 4 + qd)];
#pragma unroll
                for (int ct = 0; ct < 2; ++ct)
                    sacc[rt][ct] = __builtin_amdgcn_mfma_f32_16x16x32_bf16(
                        kf, qf[ct][kt], sacc[rt][ct], 0, 0, 0);
            }

        // ---- online softmax per q-column (log2 domain, rescale-skip) ----
#pragma unroll
        for (int ct = 0; ct < 2; ++ct) {
            float mx = sacc[0][ct][0];
#pragma unroll
            for (int rt = 0; rt < 8; ++rt)
#pragma unroll
                for (int r = 0; r < 4; ++r)
                    mx = fmaxf(mx, sacc[rt][ct][r]);
            mx = fmaxf(mx, __shfl_xor(mx, 16, 64));
            mx = fmaxf(mx, __shfl_xor(mx, 32, 64));
            const float mn = fmaxf(m[ct], mx);
            const bool up = __any(mn > m[ct]);  // wave-uniform guard
            float rs = 0.f;
#pragma unroll
            for (int rt = 0; rt < 8; ++rt) {
                float p0 = exp2f(sacc[rt][ct][0] - mn);
                float p1 = exp2f(sacc[rt][ct][1] - mn);
                float p2 = exp2f(sacc[rt][ct][2] - mn);
                float p3 = exp2f(sacc[rt][ct][3] - mn);
                rs += (p0 + p1) + (p2 + p3);
                *(ushort4*)&Pl[wv][(ct * 16 + lo) * PSTR + rt * 16 + qd * 4] =
                    pack4f(p0, p1, p2, p3);
            }
            rs += __shfl_xor(rs, 16, 64);
            rs += __shfl_xor(rs, 32, 64);
            if (up) {                           // max moved (rare after warmup)
                const float corr = exp2f(m[ct] - mn);
                l[ct] *= corr;
#pragma unroll
                for (int rt = 0; rt < 4; ++rt)
#pragma unroll
                    for (int r = 0; r < 4; ++r) oacc[rt][ct][r] *= corr;
                m[ct] = mn;
            }
            l[ct] += rs;
        }

        // ---- O^T += V^T P^T : A=Vl[dh][key], B=Pl[q][key], kt2 0..3 ----
#pragma unroll
        for (int kt2 = 0; kt2 < 4; ++kt2) {
            bf16x8 pf[2];
#pragma unroll
            for (int ct = 0; ct < 2; ++ct)
                pf[ct] = *(const bf16x8*)&Pl[wv][(ct * 16 + lo) * PSTR
                                                 + kt2 * 32 + qd * 8];
#pragma unroll
            for (int rt = 0; rt < 4; ++rt) {
                bf16x8 vf = *(const bf16x8*)&Vl[swzV(rt * 16 + lo, kt2 * 4 + qd)];
#pragma unroll
                for (int ct = 0; ct < 2; ++ct)
                    oacc[rt][ct] = __builtin_amdgcn_mfma_f32_16x16x32_bf16(
                        vf, pf[ct], oacc[rt][ct], 0, 0, 0);
            }
        }
    }

    // ---- epilogue ----
#pragma unroll
    for (int ct = 0; ct < 2; ++ct) {
        const float inv = 1.0f / l[ct];
        const int s = q0 + ct * 16 + lo;
#pragma unroll
        for (int rt = 0; rt < 4; ++rt) {
            float4 o;
            o.x = oacc[rt][ct][0] * inv; o.y = oacc[rt][ct][1] * inv;
            o.z = oacc[rt][ct][2] * inv; o.w = oacc[rt][ct][3] * inv;
            *(float4*)&out[((size_t)n * SS + s) * DM + h * DHd
                           + rt * 16 + qd * 4] = o;
        }
    }
}

extern "C" void kernel_launch(void* const* d_in, const int* in_sizes, int n_in,
                              void* d_out, int out_size, void* d_ws, size_t ws_size,
                              hipStream_t stream) {
    const float* seq = (const float*)d_in[0];
    const float* Wq  = (const float*)d_in[1];
    const float* bq  = (const float*)d_in[2];
    const float* Wk  = (const float*)d_in[3];
    const float* bk  = (const float*)d_in[4];
    const float* Wv  = (const float*)d_in[5];
    const float* bv  = (const float*)d_in[6];
    float* out = (float*)d_out;

    const size_t per = (size_t)NB * NH * SS * DHd;  // 4.19M bf16 = 8.4 MB each
    unsigned short* Q  = (unsigned short*)d_ws;
    unsigned short* K  = Q + per;
    unsigned short* Vt = K + per;

    qkv_proj<<<512, 256, 0, stream>>>(seq, Wq, bq, Wk, bk, Wv, bv, Q, K, Vt);
    attn<<<512, 256, 0, stream>>>(Q, K, Vt, out);
}